// Round 1
// baseline (1638.498 us; speedup 1.0000x reference)
//
#include <hip/hip_runtime.h>
#include <hip/hip_bf16.h>
#include <hip/hip_fp8.h>
#include <cstdint>
#include <cstddef>

// Problem constants (from reference)
#define E_ 8
#define H_ 2048
#define I_ 5632
#define N1_ (2 * I_)
#define G_ 128
#define T_ 256
#define SLOT_CAP 768  // >= sum_e ceil(cnt_e/16)*16 ; max possible = 512 + 8*15 = 632

typedef __attribute__((ext_vector_type(4))) float f32x4;
typedef __attribute__((ext_vector_type(8))) __bf16 bf16x8;

// Workspace layout (bytes). Total ~11.3 MB.
#define WS_CNT 0                       // 8 ints
#define WS_OFFS 64                     // 9 ints (padded prefix offsets)
#define WS_TOKEN 128                   // SLOT_CAP ints
#define WS_GATE (128 + SLOT_CAP * 4)   // SLOT_CAP floats
#define WS_A1 8192                     // SLOT_CAP * H_ bf16 = 3,145,728 B
#define WS_A2 (8192 + SLOT_CAP * H_ * 2)  // SLOT_CAP * I_ bf16 = 8,650,752 B

__device__ __forceinline__ uint32_t pack_bf16x2(float a, float b) {
  union { float f; uint32_t u; } ua, ub;
  ua.f = a; ub.f = b;
  uint32_t ra = (ua.u + 0x7FFFu + ((ua.u >> 16) & 1u)) >> 16;       // RTNE bf16, low half
  uint32_t rb = (ub.u + 0x7FFFu + ((ub.u >> 16) & 1u)) & 0xFFFF0000u; // high half
  return ra | rb;
}

__device__ __forceinline__ float fp8_qdq1(float x) {
  // reference: clip(x, +-448) -> e4m3fn (RTNE) -> float
  x = fminf(fmaxf(x, -448.0f), 448.0f);
  __hip_fp8_e4m3 q(x);  // OCP e4m3fn on gfx950
  return (float)q;
}

// ---------------- routing: softmax top-2, per-expert compacted slot lists ----
__global__ void routing_kernel(const float* __restrict__ logits,
                               int* __restrict__ cnt, int* __restrict__ offs,
                               int* __restrict__ token_of, float* __restrict__ gate_of) {
  __shared__ int s_cnt[E_];
  __shared__ int s_off[E_ + 1];
  int t = threadIdx.x;  // one thread per token, T_ == blockDim.x == 256
  if (t < E_) s_cnt[t] = 0;
  __syncthreads();
  float l[E_];
#pragma unroll
  for (int e = 0; e < E_; e++) l[e] = logits[t * E_ + e];
  int i0 = 0;
#pragma unroll
  for (int e = 1; e < E_; e++) if (l[e] > l[i0]) i0 = e;  // ties -> lower idx (jax top_k)
  int i1 = (i0 == 0) ? 1 : 0;
#pragma unroll
  for (int e = 0; e < E_; e++) if (e != i0 && l[e] > l[i1]) i1 = e;
  // renormalized gates: p0/(p0+p1) = 1/(1+exp(l1-l0)), stable since l1<=l0
  float g0 = 1.0f / (1.0f + expf(l[i1] - l[i0]));
  float g1 = 1.0f - g0;
  int s0 = atomicAdd(&s_cnt[i0], 1);
  int s1 = atomicAdd(&s_cnt[i1], 1);
  __syncthreads();
  if (t == 0) {
    s_off[0] = 0;
    for (int e = 0; e < E_; e++) s_off[e + 1] = s_off[e] + ((s_cnt[e] + 15) & ~15);
  }
  __syncthreads();
  token_of[s_off[i0] + s0] = t;
  gate_of[s_off[i0] + s0] = g0;
  token_of[s_off[i1] + s1] = t;
  gate_of[s_off[i1] + s1] = g1;
  if (t < E_) cnt[t] = s_cnt[t];
  if (t < E_ + 1) offs[t] = s_off[t];
  // pad slots: token 0, gate 0 (benign); disjoint from real slots
  for (int idx = t; idx < SLOT_CAP; idx += 256) {
    int e = 0;
    while (e < E_ && idx >= s_off[e + 1]) e++;
    bool pad = true;
    if (e < E_) pad = ((idx - s_off[e]) >= s_cnt[e]);
    if (pad) { token_of[idx] = 0; gate_of[idx] = 0.0f; }
  }
}

// ---------------- gather + fp8 qdq -> A1 (bf16, zero-padded rows) -----------
__global__ void gather_kernel(const float* __restrict__ hidden,
                              const float* __restrict__ is1,
                              const int* __restrict__ cnt,
                              const int* __restrict__ offs,
                              const int* __restrict__ token_of,
                              __hip_bfloat16* __restrict__ A1) {
  int sg = blockIdx.x;  // global padded slot
  int e = 0;
  while (e < E_ && sg >= offs[e + 1]) e++;
  bool pad = true;
  int t = 0;
  if (e < E_) {
    int local = sg - offs[e];
    if (local < cnt[e]) { pad = false; t = token_of[sg]; }
  }
  uint4 u;
  if (pad) {
    u.x = u.y = u.z = u.w = 0u;
  } else {
    float s1 = is1[e];
    const float4* hp = (const float4*)(hidden + (size_t)t * H_ + threadIdx.x * 8);
    float4 x0 = hp[0], x1 = hp[1];
    float q0 = fp8_qdq1(x0.x / s1), q1 = fp8_qdq1(x0.y / s1);
    float q2 = fp8_qdq1(x0.z / s1), q3 = fp8_qdq1(x0.w / s1);
    float q4 = fp8_qdq1(x1.x / s1), q5 = fp8_qdq1(x1.y / s1);
    float q6 = fp8_qdq1(x1.z / s1), q7 = fp8_qdq1(x1.w / s1);
    u.x = pack_bf16x2(q0, q1); u.y = pack_bf16x2(q2, q3);
    u.z = pack_bf16x2(q4, q5); u.w = pack_bf16x2(q6, q7);
  }
  ((uint4*)(A1 + (size_t)sg * H_))[threadIdx.x] = u;
}

// ---------------- fc1: bf16 MFMA GEMM + fused SwiGLU + qdq -> A2 ------------
// block: 256 thr = 4 waves. waves 0,1 -> up cols [j0, j0+32); waves 2,3 -> gate
// cols [I_+j0, I_+j0+32). Weights read once from global straight into B-frags.
__global__ __launch_bounds__(256) void fc1_kernel(
    const int* __restrict__ w1, const float* __restrict__ w1s,
    const float* __restrict__ is1v, const float* __restrict__ is2v,
    const int* __restrict__ cnt, const int* __restrict__ offs,
    const __hip_bfloat16* __restrict__ A1, __hip_bfloat16* __restrict__ A2) {
  int e = blockIdx.y;
  int c_n = cnt[e];
  if (c_n == 0) return;
  int nch = (c_n + 15) >> 4;          // active 16-row chunks (<=16)
  int base_slot = offs[e];
  int j0 = blockIdx.x * 32;
  int wave = threadIdx.x >> 6, lane = threadIdx.x & 63;
  int lm = lane & 15, kq = lane >> 4;
  int jj = j0 + (wave & 1) * 16 + lm;
  int n = (wave >> 1) ? (I_ + jj) : jj;
  const int* wcol = w1 + (size_t)e * H_ * N1_ + n;
  const float* scol = w1s + (size_t)e * (H_ / G_) * N1_ + n;
  const __hip_bfloat16* abase = A1 + (size_t)base_slot * H_;
  f32x4 acc[16];
#pragma unroll
  for (int c = 0; c < 16; c++) acc[c] = (f32x4){0.f, 0.f, 0.f, 0.f};
  float sc = 0.f;
  for (int ks = 0; ks < H_ / 32; ks++) {
    if ((ks & 3) == 0) sc = scol[(size_t)(ks >> 2) * N1_];
    int kb = ks * 32 + kq * 8;
    int w[8];
#pragma unroll
    for (int i = 0; i < 8; i++) w[i] = wcol[(size_t)(kb + i) * N1_];
    union { bf16x8 v; uint32_t u[4]; } bf;
#pragma unroll
    for (int i = 0; i < 4; i++)
      bf.u[i] = pack_bf16x2((float)w[2 * i] * sc, (float)w[2 * i + 1] * sc);
#pragma unroll
    for (int c = 0; c < 16; c++) {
      if (c < nch) {
        union { bf16x8 v; uint4 u; } a;
        a.u = *(const uint4*)(abase + (size_t)(c * 16 + lm) * H_ + kb);
        acc[c] = __builtin_amdgcn_mfma_f32_16x16x32_bf16(a.v, bf.v, acc[c], 0, 0, 0);
      }
    }
  }
  // epilogue: exchange up/gate tiles through LDS, SwiGLU, qdq(s2) -> A2 bf16
  float s1 = is1v[e], s2 = is2v[e];
  __shared__ float ls[16][68];  // pitch 68 floats -> 2-way bank alias (free)
  int colw = (wave >> 1) * 32 + (wave & 1) * 16 + lm;
#pragma unroll
  for (int c = 0; c < 16; c++) {
    if (c >= nch) break;
#pragma unroll
    for (int i = 0; i < 4; i++) ls[kq * 4 + i][colw] = acc[c][i] * s1;
    __syncthreads();
    for (int v = threadIdx.x; v < 512; v += 256) {
      int r = v >> 5, j2 = v & 31;
      float up = ls[r][j2], gt = ls[r][32 + j2];
      float hh = up * (gt / (1.0f + expf(-gt)));  // up * silu(gate)
      float q = fp8_qdq1(hh / s2);
      A2[(size_t)(base_slot + c * 16 + r) * I_ + (j0 + j2)] = __float2bfloat16(q);
    }
    __syncthreads();
  }
}

// ---------------- fc2: bf16 MFMA GEMM, split-K x4, atomic scatter-add -------
__global__ __launch_bounds__(256) void fc2_kernel(
    const int* __restrict__ w2, const float* __restrict__ w2s,
    const float* __restrict__ is2v,
    const int* __restrict__ cnt, const int* __restrict__ offs,
    const int* __restrict__ token_of, const float* __restrict__ gate_of,
    const __hip_bfloat16* __restrict__ A2, float* __restrict__ out) {
  int e = blockIdx.y;
  int c_n = cnt[e];
  if (c_n == 0) return;
  int nch = (c_n + 15) >> 4;
  int base_slot = offs[e];
  int n0 = blockIdx.x * 64;
  int wave = threadIdx.x >> 6, lane = threadIdx.x & 63;
  int lm = lane & 15, kq = lane >> 4;
  int n = n0 + wave * 16 + lm;
  const int* wcol = w2 + (size_t)e * I_ * H_ + n;
  const float* scol = w2s + (size_t)e * (I_ / G_) * H_ + n;
  const __hip_bfloat16* abase = A2 + (size_t)base_slot * I_;
  f32x4 acc[16];
#pragma unroll
  for (int c = 0; c < 16; c++) acc[c] = (f32x4){0.f, 0.f, 0.f, 0.f};
  int ks0 = blockIdx.z * 44;  // 4 slices * 44 k32-steps = 176 = I_/32; 44%4==0
  float sc = 0.f;
  for (int ks = ks0; ks < ks0 + 44; ks++) {
    if ((ks & 3) == 0) sc = scol[(size_t)(ks >> 2) * H_];
    int kb = ks * 32 + kq * 8;
    int w[8];
#pragma unroll
    for (int i = 0; i < 8; i++) w[i] = wcol[(size_t)(kb + i) * H_];
    union { bf16x8 v; uint32_t u[4]; } bf;
#pragma unroll
    for (int i = 0; i < 4; i++)
      bf.u[i] = pack_bf16x2((float)w[2 * i] * sc, (float)w[2 * i + 1] * sc);
#pragma unroll
    for (int c = 0; c < 16; c++) {
      if (c < nch) {
        union { bf16x8 v; uint4 u; } a;
        a.u = *(const uint4*)(abase + (size_t)(c * 16 + lm) * I_ + kb);
        acc[c] = __builtin_amdgcn_mfma_f32_16x16x32_bf16(a.v, bf.v, acc[c], 0, 0, 0);
      }
    }
  }
  float s2 = is2v[e];
#pragma unroll
  for (int c = 0; c < 16; c++) {
    if (c < nch) {
#pragma unroll
      for (int i = 0; i < 4; i++) {
        int slot = c * 16 + kq * 4 + i;
        if (slot < c_n) {
          int t = token_of[base_slot + slot];
          float gv = gate_of[base_slot + slot];
          atomicAdd(out + (size_t)t * H_ + n, acc[c][i] * s2 * gv);
        }
      }
    }
  }
}

extern "C" void kernel_launch(void* const* d_in, const int* in_sizes, int n_in,
                              void* d_out, int out_size, void* d_ws, size_t ws_size,
                              hipStream_t stream) {
  const float* hidden = (const float*)d_in[0];
  const float* logits = (const float*)d_in[1];
  const int* w1 = (const int*)d_in[2];
  const int* w2 = (const int*)d_in[3];
  const float* w1s = (const float*)d_in[4];
  const float* w2s = (const float*)d_in[5];
  const float* is1 = (const float*)d_in[6];
  const float* is2 = (const float*)d_in[7];
  float* out = (float*)d_out;
  char* ws = (char*)d_ws;
  int* cnt = (int*)(ws + WS_CNT);
  int* offs = (int*)(ws + WS_OFFS);
  int* token_of = (int*)(ws + WS_TOKEN);
  float* gate_of = (float*)(ws + WS_GATE);
  __hip_bfloat16* A1 = (__hip_bfloat16*)(ws + WS_A1);
  __hip_bfloat16* A2 = (__hip_bfloat16*)(ws + WS_A2);

  hipMemsetAsync(d_out, 0, (size_t)T_ * H_ * sizeof(float), stream);
  routing_kernel<<<1, 256, 0, stream>>>(logits, cnt, offs, token_of, gate_of);
  gather_kernel<<<SLOT_CAP, 256, 0, stream>>>(hidden, is1, cnt, offs, token_of, A1);
  fc1_kernel<<<dim3(I_ / 32, E_), 256, 0, stream>>>(w1, w1s, is1, is2, cnt, offs, A1, A2);
  fc2_kernel<<<dim3(H_ / 64, E_, 4), 256, 0, stream>>>(w2, w2s, is2, cnt, offs, token_of,
                                                       gate_of, A2, out);
}